// Round 3
// baseline (18.685 us; speedup 1.0000x reference)
//
#include <hip/hip_runtime.h>

#define NG 2048
#define WIMG 256
#define HIMG 256
#define TILE 16
#define NTH 512
#define NCHUNK (NG / NTH)      // 4
#define NWAVES (NTH / 64)      // 8
#define LOG2E 1.4426950408889634f
#define LOG2EPS -23.25f        // 2^-23.25 ~ 1e-7 per-gaussian skip epsilon

__global__ __launch_bounds__(512) void gi_fused_kernel(
    const float* __restrict__ xyz,      // (3, N, 2)
    const float* __restrict__ chol,     // (3, N, 3)
    const float* __restrict__ opacity,  // (N, 1)
    const float* __restrict__ feat,     // (N, 3)
    const int*   __restrict__ fidx,
    float*       __restrict__ out)      // (1, 3, H, W)
{
    __shared__ float4 sP[NG];              // 32 KB  (cx, cy, na, nb)
    __shared__ float4 sQ[NG];              // 32 KB  (nc, k,  cr, cg)
    __shared__ float  sB[NG];              // 8 KB   (cb)
    __shared__ float  sAcc[3][256];        // 3 KB   split-K partials
    __shared__ int    swcnt[NCHUNK][NWAVES];

    const int tid  = threadIdx.x;
    const int lane = tid & 63;
    const int wid  = tid >> 6;
    const int bx   = blockIdx.x & 15;
    const int by   = blockIdx.x >> 4;
    const float tx0 = (float)(bx * TILE), tx1 = tx0 + (float)TILE;
    const float ty0 = (float)(by * TILE), ty1 = ty0 + (float)TILE;

    const float t  = (float)(*fidx) * (1.0f / 7.0f);   // linspace(0,1,8)[idx]
    const float t2 = t * t;

    // ---------- phase 1: prep 4 gaussians per thread, fully in registers ----
    float4 rP[NCHUNK], rQ[NCHUNK];
    float  rB[NCHUNK];
    unsigned long long msk[NCHUNK];
    bool   keep[NCHUNK];

    const float2* xy2 = (const float2*)xyz;

#pragma unroll
    for (int c = 0; c < NCHUNK; ++c) {
        const int g = c * NTH + tid;
        float2 a0 = xy2[g];
        float2 a1 = xy2[NG + g];
        float2 a2 = xy2[2 * NG + g];
        float ux = fmaf(t2, a2.x, fmaf(t, a1.x, a0.x));
        float uy = fmaf(t2, a2.y, fmaf(t, a1.y, a0.y));
        // tanh via native exp2/rcp
        float ex = __builtin_amdgcn_exp2f(2.0f * LOG2E * ux);
        float ey = __builtin_amdgcn_exp2f(2.0f * LOG2E * uy);
        float mx = (ex - 1.0f) * __builtin_amdgcn_rcpf(ex + 1.0f);
        float my = (ey - 1.0f) * __builtin_amdgcn_rcpf(ey + 1.0f);
        float cx = 128.0f * (mx + 1.0f);
        float cy = 128.0f * (my + 1.0f);

        const float* c0 = chol + g * 3;
        float l1 = fmaf(t2, c0[2*NG*3+0], fmaf(t, c0[NG*3+0], c0[0])) + 0.5f;
        float l2 = fmaf(t2, c0[2*NG*3+1], fmaf(t, c0[NG*3+1], c0[1]));
        float l3 = fmaf(t2, c0[2*NG*3+2], fmaf(t, c0[NG*3+2], c0[2])) + 0.5f;

        float s11 = l1 * l1;
        float s12 = l1 * l2;
        float s22 = fmaf(l2, l2, l3 * l3);
        float det = fmaf(s11, s22, -s12 * s12);
        float rdet = __builtin_amdgcn_rcpf(det);
        float A =  s22 * rdet;
        float B = -s12 * rdet;
        float C =  s11 * rdet;

        float opac = __builtin_amdgcn_rcpf(1.0f + __builtin_amdgcn_exp2f(-LOG2E * opacity[g]));
        float k  = __builtin_amdgcn_logf(opac);        // log2(opac)

        float cr = __builtin_amdgcn_rcpf(1.0f + __builtin_amdgcn_exp2f(-LOG2E * feat[g*3+0]));
        float cg = __builtin_amdgcn_rcpf(1.0f + __builtin_amdgcn_exp2f(-LOG2E * feat[g*3+1]));
        float cb = __builtin_amdgcn_rcpf(1.0f + __builtin_amdgcn_exp2f(-LOG2E * feat[g*3+2]));

        rP[c] = make_float4(cx, cy, -0.5f * LOG2E * A, -LOG2E * B);
        rQ[c] = make_float4(-0.5f * LOG2E * C, k, cr, cg);
        rB[c] = cb;

        // conservative tile cull: sigma >= 0.5*lambda_min(prec)*d^2
        float dxt = fmaxf(fmaxf(tx0 - cx, cx - tx1), 0.0f);
        float dyt = fmaxf(fmaxf(ty0 - cy, cy - ty1), 0.0f);
        float d2  = fmaf(dxt, dxt, dyt * dyt);
        float amc = A - C;
        float lm  = 0.5f * (A + C) - sqrtf(fmaf(0.25f * amc, amc, B * B));
        float bnd = fmaf(-0.5f * LOG2E * lm, d2, k);
        bool  drop = (lm > 0.0f) && (bnd < LOG2EPS);   // NaN-safe: keep on NaN
        keep[c] = !drop;

        msk[c] = __ballot(keep[c]);
        if (lane == 0) swcnt[c][wid] = __popcll(msk[c]);
    }

    __syncthreads();

    // ---------- phase 2: single-pass deterministic compaction ----
    int cw[NCHUNK][NWAVES];
#pragma unroll
    for (int c = 0; c < NCHUNK; ++c)
#pragma unroll
        for (int w = 0; w < NWAVES; ++w)
            cw[c][w] = swcnt[c][w];

    int chunkBase[NCHUNK];
    int run = 0;
#pragma unroll
    for (int c = 0; c < NCHUNK; ++c) {
        chunkBase[c] = run;
#pragma unroll
        for (int w = 0; w < NWAVES; ++w) run += cw[c][w];
    }
    const int cnt = run;

#pragma unroll
    for (int c = 0; c < NCHUNK; ++c) {
        if (keep[c]) {
            int base = chunkBase[c];
#pragma unroll
            for (int w = 0; w < NWAVES; ++w)
                if (w < wid) base += cw[c][w];
            int idx = base + __popcll(msk[c] & ((1ULL << lane) - 1ULL));
            sP[idx] = rP[c];
            sQ[idx] = rQ[c];
            sB[idx] = rB[c];
        }
    }

    __syncthreads();

    // ---------- phase 3: split-K render ----
    const int p   = tid & 255;             // pixel within tile
    const int sk  = tid >> 8;              // K-group: 0 = even survivors, 1 = odd
    const float px = (float)(bx * TILE + (p & 15)) + 0.5f;
    const float py = (float)(by * TILE + (p >> 4)) + 0.5f;

    float accR = 0.0f, accG = 0.0f, accB = 0.0f;
#pragma unroll 2
    for (int s = sk; s < cnt; s += 2) {
        float4 P = sP[s];
        float4 Q = sQ[s];
        float  cb = sB[s];
        float dx = px - P.x;
        float dy = py - P.y;
        float arg = fmaf(P.z, dx * dx,
                    fmaf(P.w, dx * dy,
                    fmaf(Q.x, dy * dy, Q.y)));
        float a = fminf(__builtin_amdgcn_exp2f(arg), 0.99f);
        accR = fmaf(a, Q.z, accR);
        accG = fmaf(a, Q.w, accG);
        accB = fmaf(a, cb, accB);
    }

    // ---------- phase 4: reduce K-groups, store ----
    __syncthreads();                       // render reads of sB done
    if (sk == 1) {
        sAcc[0][p] = accR;
        sAcc[1][p] = accG;
        sAcc[2][p] = accB;
    }
    __syncthreads();
    if (sk == 0) {
        const int pix = (by * TILE + (p >> 4)) * WIMG + bx * TILE + (p & 15);
        float r = accR + sAcc[0][p];
        float g = accG + sAcc[1][p];
        float b = accB + sAcc[2][p];
        out[pix]                   = fminf(fmaxf(r, 0.0f), 1.0f);
        out[HIMG * WIMG + pix]     = fminf(fmaxf(g, 0.0f), 1.0f);
        out[2 * HIMG * WIMG + pix] = fminf(fmaxf(b, 0.0f), 1.0f);
    }
}

extern "C" void kernel_launch(void* const* d_in, const int* in_sizes, int n_in,
                              void* d_out, int out_size, void* d_ws, size_t ws_size,
                              hipStream_t stream) {
    const float* xyz     = (const float*)d_in[0];
    const float* chol    = (const float*)d_in[1];
    const float* opacity = (const float*)d_in[2];
    const float* feat    = (const float*)d_in[3];
    const int*   fidx    = (const int*)d_in[4];
    float*       out     = (float*)d_out;

    hipLaunchKernelGGL(gi_fused_kernel,
                       dim3((WIMG / TILE) * (HIMG / TILE)), dim3(NTH),
                       0, stream,
                       xyz, chol, opacity, feat, fidx, out);
}

// Round 4
// 17.794 us; speedup vs baseline: 1.0501x; 1.0501x over previous
//
#include <hip/hip_runtime.h>

#define NG 2048
#define WIMG 256
#define HIMG 256
#define TILE 16
#define NSLICE 8
#define GS (NG / NSLICE)        // 256 gaussians per slice
#define LOG2E 1.4426950408889634f
#define LOG2EPS -23.25f         // 2^-23.25 ~ 1e-7 per-gaussian skip epsilon

// ---------------- prep: fold per-gaussian params (8 blocks x 256) -----------
__global__ __launch_bounds__(256) void gi_prep_kernel(
    const float* __restrict__ xyz,      // (3, N, 2)
    const float* __restrict__ chol,     // (3, N, 3)
    const float* __restrict__ opacity,  // (N, 1)
    const float* __restrict__ feat,     // (N, 3)
    const int*   __restrict__ fidx,
    float4* __restrict__ p0,            // cx, cy, na, nb
    float4* __restrict__ p1,            // nc, k,  cr, cg
    float2* __restrict__ p2)            // cb, r2max
{
    const int g = blockIdx.x * 256 + threadIdx.x;
    const float t  = (float)(*fidx) * (1.0f / 7.0f);   // linspace(0,1,8)[idx]
    const float t2 = t * t;

    const float2* xy2 = (const float2*)xyz;
    float2 a0 = xy2[g];
    float2 a1 = xy2[NG + g];
    float2 a2 = xy2[2 * NG + g];

    float ux = fmaf(t2, a2.x, fmaf(t, a1.x, a0.x));
    float uy = fmaf(t2, a2.y, fmaf(t, a1.y, a0.y));
    float ex = __builtin_amdgcn_exp2f(2.0f * LOG2E * ux);
    float ey = __builtin_amdgcn_exp2f(2.0f * LOG2E * uy);
    float mx = (ex - 1.0f) * __builtin_amdgcn_rcpf(ex + 1.0f);
    float my = (ey - 1.0f) * __builtin_amdgcn_rcpf(ey + 1.0f);
    float cx = 128.0f * (mx + 1.0f);
    float cy = 128.0f * (my + 1.0f);

    const float* c0 = chol + g * 3;
    float l1 = fmaf(t2, c0[2*NG*3+0], fmaf(t, c0[NG*3+0], c0[0])) + 0.5f;
    float l2 = fmaf(t2, c0[2*NG*3+1], fmaf(t, c0[NG*3+1], c0[1]));
    float l3 = fmaf(t2, c0[2*NG*3+2], fmaf(t, c0[NG*3+2], c0[2])) + 0.5f;

    float s11 = l1 * l1;
    float s12 = l1 * l2;
    float s22 = fmaf(l2, l2, l3 * l3);
    float det = fmaf(s11, s22, -s12 * s12);
    float rdet = __builtin_amdgcn_rcpf(det);
    float A =  s22 * rdet;
    float B = -s12 * rdet;
    float C =  s11 * rdet;

    float opac = __builtin_amdgcn_rcpf(1.0f + __builtin_amdgcn_exp2f(-LOG2E * opacity[g]));
    float k  = __builtin_amdgcn_logf(opac);            // log2(opac)

    float cr = __builtin_amdgcn_rcpf(1.0f + __builtin_amdgcn_exp2f(-LOG2E * feat[g*3+0]));
    float cg = __builtin_amdgcn_rcpf(1.0f + __builtin_amdgcn_exp2f(-LOG2E * feat[g*3+1]));
    float cb = __builtin_amdgcn_rcpf(1.0f + __builtin_amdgcn_exp2f(-LOG2E * feat[g*3+2]));

    float amc = A - C;
    float lm  = 0.5f * (A + C) - sqrtf(fmaf(0.25f * amc, amc, B * B));
    float r2max = (k - LOG2EPS) * __builtin_amdgcn_rcpf(0.5f * LOG2E * lm);
    if (!(lm > 0.0f)) r2max = 3.4e38f;   // NaN / non-PD safe: keep everywhere

    p0[g] = make_float4(cx, cy, -0.5f * LOG2E * A, -LOG2E * B);
    p1[g] = make_float4(-0.5f * LOG2E * C, k, cr, cg);
    p2[g] = make_float2(cb, r2max);
}

// ------------- split-K render: 2048 blocks = 256 tiles x 8 slices -----------
__global__ __launch_bounds__(256) void gi_render_part(
    const float4* __restrict__ p0,
    const float4* __restrict__ p1,
    const float2* __restrict__ p2,
    float*        __restrict__ part)    // (NSLICE, 3, 65536)
{
    __shared__ float4 sP[GS];
    __shared__ float4 sQ[GS];
    __shared__ float  sB[GS];
    __shared__ int    swcnt[4];

    const int tid    = threadIdx.x;
    const int lane   = tid & 63;
    const int wid    = tid >> 6;
    const int tileId = blockIdx.x & 255;
    const int slice  = blockIdx.x >> 8;
    const int bx     = tileId & 15;
    const int by     = tileId >> 4;
    const float tx0 = (float)(bx * TILE), tx1 = tx0 + (float)TILE;
    const float ty0 = (float)(by * TILE), ty1 = ty0 + (float)TILE;

    // one gaussian per thread: cull vs this tile
    const int g = slice * GS + tid;
    float4 P0 = p0[g];
    float4 P1 = p1[g];
    float2 P2 = p2[g];

    float dxt = fmaxf(fmaxf(tx0 - P0.x, P0.x - tx1), 0.0f);
    float dyt = fmaxf(fmaxf(ty0 - P0.y, P0.y - ty1), 0.0f);
    float d2  = fmaf(dxt, dxt, dyt * dyt);
    bool keep = !(d2 > P2.y);            // NaN-safe: keeps on NaN

    unsigned long long m = __ballot(keep);
    if (lane == 0) swcnt[wid] = __popcll(m);
    __syncthreads();
    int base = 0;
#pragma unroll
    for (int w = 0; w < 4; ++w)
        if (w < wid) base += swcnt[w];
    const int cnt = swcnt[0] + swcnt[1] + swcnt[2] + swcnt[3];
    if (keep) {
        int idx = base + __popcll(m & ((1ULL << lane) - 1ULL));
        sP[idx] = P0;
        sQ[idx] = P1;
        sB[idx] = P2.x;
    }
    __syncthreads();

    const float px = (float)(bx * TILE + (tid & 15)) + 0.5f;
    const float py = (float)(by * TILE + (tid >> 4)) + 0.5f;

    float accR = 0.0f, accG = 0.0f, accB = 0.0f;
    for (int s = 0; s < cnt; ++s) {
        float4 P = sP[s];
        float4 Q = sQ[s];
        float  cb = sB[s];
        float dx = px - P.x;
        float dy = py - P.y;
        float arg = fmaf(P.z, dx * dx,
                    fmaf(P.w, dx * dy,
                    fmaf(Q.x, dy * dy, Q.y)));
        float a = fminf(__builtin_amdgcn_exp2f(arg), 0.99f);
        accR = fmaf(a, Q.z, accR);
        accG = fmaf(a, Q.w, accG);
        accB = fmaf(a, cb, accB);
    }

    const int pix = (by * TILE + (tid >> 4)) * WIMG + bx * TILE + (tid & 15);
    part[((slice * 3 + 0) << 16) + pix] = accR;
    part[((slice * 3 + 1) << 16) + pix] = accG;
    part[((slice * 3 + 2) << 16) + pix] = accB;
}

// ---------------- reduce 8 slices + clip (256 blocks x 256) -----------------
__global__ __launch_bounds__(256) void gi_reduce(
    const float* __restrict__ part,
    float*       __restrict__ out)
{
    const int p = blockIdx.x * 256 + threadIdx.x;   // 0..65535
    float r = 0.0f, g = 0.0f, b = 0.0f;
#pragma unroll
    for (int s = 0; s < NSLICE; ++s) {
        r += part[((s * 3 + 0) << 16) + p];
        g += part[((s * 3 + 1) << 16) + p];
        b += part[((s * 3 + 2) << 16) + p];
    }
    out[p]                   = fminf(fmaxf(r, 0.0f), 1.0f);
    out[(1 << 16) + p]       = fminf(fmaxf(g, 0.0f), 1.0f);
    out[(2 << 16) + p]       = fminf(fmaxf(b, 0.0f), 1.0f);
}

extern "C" void kernel_launch(void* const* d_in, const int* in_sizes, int n_in,
                              void* d_out, int out_size, void* d_ws, size_t ws_size,
                              hipStream_t stream) {
    const float* xyz     = (const float*)d_in[0];
    const float* chol    = (const float*)d_in[1];
    const float* opacity = (const float*)d_in[2];
    const float* feat    = (const float*)d_in[3];
    const int*   fidx    = (const int*)d_in[4];
    float*       out     = (float*)d_out;

    float4* p0   = (float4*)d_ws;                         // 32 KB
    float4* p1   = (float4*)((char*)d_ws + NG * 16);      // 32 KB
    float2* p2   = (float2*)((char*)d_ws + NG * 32);      // 16 KB
    float*  part = (float*)((char*)d_ws + NG * 40);       // 6.29 MB

    hipLaunchKernelGGL(gi_prep_kernel, dim3(NG / 256), dim3(256), 0, stream,
                       xyz, chol, opacity, feat, fidx, p0, p1, p2);
    hipLaunchKernelGGL(gi_render_part, dim3(256 * NSLICE), dim3(256), 0, stream,
                       p0, p1, p2, part);
    hipLaunchKernelGGL(gi_reduce, dim3(256), dim3(256), 0, stream, part, out);
}

// Round 5
// 17.240 us; speedup vs baseline: 1.0838x; 1.0321x over previous
//
#include <hip/hip_runtime.h>

#define NG 2048
#define WIMG 256
#define HIMG 256
#define TILE 16
#define CAP 1280
#define LOG2E 1.4426950408889634f
#define LOG2EPS -23.25f   // 2^-23.25 ~ 1e-7 : per-gaussian skip epsilon

__device__ __forceinline__ float sigmoidf_(float x) {
    return 1.0f / (1.0f + __expf(-x));
}

__global__ __launch_bounds__(256) void GaussianImage_render_kernel(
    const float* __restrict__ xyz,      // (3, N, 2)
    const float* __restrict__ chol,     // (3, N, 3)
    const float* __restrict__ opacity,  // (N, 1)
    const float* __restrict__ feat,     // (N, 3)
    const int*   __restrict__ fidx,     // scalar frame index
    float*       __restrict__ out)      // (1, 3, H, W)
{
    // survivor list in LDS: 9 params packed as float4+float4+float
    __shared__ float4 sP[CAP];   // cx, cy, na, nb
    __shared__ float4 sQ[CAP];   // nc, k,  cr, cg
    __shared__ float  sB[CAP];   // cb
    __shared__ int    swcnt[4];

    const int tid  = threadIdx.x;
    const int lane = tid & 63;
    const int wid  = tid >> 6;
    const int bx   = blockIdx.x & 15;
    const int by   = blockIdx.x >> 4;
    const int ix   = bx * TILE + (tid & 15);
    const int iy   = by * TILE + (tid >> 4);
    const float px = (float)ix + 0.5f;
    const float py = (float)iy + 0.5f;
    const float tx0 = (float)(bx * TILE);
    const float ty0 = (float)(by * TILE);

    const float t  = (float)(*fidx) * (1.0f / 7.0f);   // linspace(0,1,8)[i]
    const float t2 = t * t;

    float accR = 0.0f, accG = 0.0f, accB = 0.0f;
    int cnt = 0;

    // inner render pass over the compacted survivor list
    auto render = [&](int n) {
#pragma unroll 2
        for (int s = 0; s < n; ++s) {
            float4 P = sP[s];
            float4 Q = sQ[s];
            float  cb = sB[s];
            float dx = px - P.x;
            float dy = py - P.y;
            // arg = log2(opac) - log2(e)*sigma   (all folded at prep time)
            float arg = fmaf(P.z, dx * dx,
                        fmaf(P.w, dx * dy,
                        fmaf(Q.x, dy * dy, Q.y)));
            float e = __builtin_amdgcn_exp2f(arg);
            float a = fminf(e, 0.99f);
            accR = fmaf(a, Q.z, accR);
            accG = fmaf(a, Q.w, accG);
            accB = fmaf(a, cb, accB);
        }
    };

    const float2* xy2 = (const float2*)xyz;

    for (int c = 0; c < NG / 256; ++c) {
        const int g = c * 256 + tid;

        // ---- per-gaussian prep (each thread owns one gaussian) ----
        float2 a0 = xy2[0 * NG + g];
        float2 a1 = xy2[1 * NG + g];
        float2 a2 = xy2[2 * NG + g];
        float mx = tanhf(fmaf(t2, a2.x, fmaf(t, a1.x, a0.x)));
        float my = tanhf(fmaf(t2, a2.y, fmaf(t, a1.y, a0.y)));
        float cx = 128.0f * (mx + 1.0f);
        float cy = 128.0f * (my + 1.0f);

        const float* c0 = chol + g * 3;
        float l1 = fmaf(t2, c0[2 * NG * 3 + 0], fmaf(t, c0[NG * 3 + 0], c0[0])) + 0.5f;
        float l2 = fmaf(t2, c0[2 * NG * 3 + 1], fmaf(t, c0[NG * 3 + 1], c0[1]));
        float l3 = fmaf(t2, c0[2 * NG * 3 + 2], fmaf(t, c0[NG * 3 + 2], c0[2])) + 0.5f;

        float s11 = l1 * l1;
        float s12 = l1 * l2;
        float s22 = fmaf(l2, l2, l3 * l3);
        float det = fmaf(s11, s22, -s12 * s12);
        float rdet = __builtin_amdgcn_rcpf(det);
        float A =  s22 * rdet;
        float B = -s12 * rdet;
        float C =  s11 * rdet;

        float opac = sigmoidf_(opacity[g]);
        float k  = __builtin_amdgcn_logf(opac);      // log2(opac)
        float na = -0.5f * LOG2E * A;
        float nb = -LOG2E * B;
        float nc = -0.5f * LOG2E * C;

        float cr = sigmoidf_(feat[g * 3 + 0]);
        float cg = sigmoidf_(feat[g * 3 + 1]);
        float cb = sigmoidf_(feat[g * 3 + 2]);

        // ---- conservative tile cull: sigma >= 0.5*lambda_min*d^2 ----
        float dxt = fmaxf(fmaxf(tx0 - cx, cx - (tx0 + (float)TILE)), 0.0f);
        float dyt = fmaxf(fmaxf(ty0 - cy, cy - (ty0 + (float)TILE)), 0.0f);
        float d2  = fmaf(dxt, dxt, dyt * dyt);
        float amc = A - C;
        float lm  = 0.5f * (A + C) - sqrtf(fmaf(0.25f * amc, amc, B * B));
        float bnd = fmaf(-0.5f * LOG2E * lm, d2, k);
        bool  drop = (lm > 0.0f) && (bnd < LOG2EPS);  // NaN-safe: keeps on NaN
        bool  keep = !drop;

        // ---- flush if the list could overflow (never hits for this data) ----
        if (cnt + 256 > CAP) {
            render(cnt);
            __syncthreads();
            cnt = 0;
        }

        // ---- deterministic ballot compaction ----
        unsigned long long m = __ballot(keep);
        if (lane == 0) swcnt[wid] = __popcll(m);
        __syncthreads();
        int base = cnt;
#pragma unroll
        for (int w = 0; w < 4; ++w)
            if (w < wid) base += swcnt[w];
        int total = swcnt[0] + swcnt[1] + swcnt[2] + swcnt[3];
        if (keep) {
            int idx = base + __popcll(m & ((1ULL << lane) - 1ULL));
            sP[idx] = make_float4(cx, cy, na, nb);
            sQ[idx] = make_float4(nc, k, cr, cg);
            sB[idx] = cb;
        }
        cnt += total;
        __syncthreads();   // list writes visible; swcnt reusable
    }

    render(cnt);

    const int pix = iy * WIMG + ix;
    out[pix]                   = fminf(fmaxf(accR, 0.0f), 1.0f);
    out[HIMG * WIMG + pix]     = fminf(fmaxf(accG, 0.0f), 1.0f);
    out[2 * HIMG * WIMG + pix] = fminf(fmaxf(accB, 0.0f), 1.0f);
}

extern "C" void kernel_launch(void* const* d_in, const int* in_sizes, int n_in,
                              void* d_out, int out_size, void* d_ws, size_t ws_size,
                              hipStream_t stream) {
    const float* xyz     = (const float*)d_in[0];
    const float* chol    = (const float*)d_in[1];
    const float* opacity = (const float*)d_in[2];
    const float* feat    = (const float*)d_in[3];
    const int*   fidx    = (const int*)d_in[4];
    float*       out     = (float*)d_out;

    hipLaunchKernelGGL(GaussianImage_render_kernel,
                       dim3((WIMG / TILE) * (HIMG / TILE)), dim3(TILE * TILE),
                       0, stream,
                       xyz, chol, opacity, feat, fidx, out);
}